// Round 8
// baseline (484.602 us; speedup 1.0000x reference)
//
#include <hip/hip_runtime.h>

// LlamaAttention (B=2,S=1024,HID=2048,NH=32,NKV=8,D=64) on gfx950.
// R4: attn 2-phase pipeline, RoPE fused into QKV-GEMM epilogue.
// R5: GEMMs 2-phase double-buffered (one barrier/k-step).
// R7: fuse cvt+4 transposes into prep_kernel; V^T written directly from
// gemm<0> epilogue (vtrans kernel + Vb dropped); attn reads V direct from
// global (L2-resident, LDS reuse=1 -> staging was pure overhead, m169).
// 4 kernels total: prep, gemm<0>, attn, gemm<1>.

typedef unsigned short u16;
typedef unsigned char  u8;
typedef unsigned int   u32;
typedef __attribute__((ext_vector_type(4))) float  f32x4;
typedef __attribute__((ext_vector_type(8))) __bf16 bf16x8;

static __device__ __forceinline__ u16 f2b(float f) {
  u32 u = __builtin_bit_cast(u32, f);
  u = u + 0x7fffu + ((u >> 16) & 1u);   // round-to-nearest-even
  return (u16)(u >> 16);
}

// async global->LDS, 16B per lane; LDS dest is wave-uniform base + lane*16.
#define GLL16(gp, lp)                                                         \
  __builtin_amdgcn_global_load_lds(                                           \
      (__attribute__((address_space(1))) u32*)(gp),                           \
      (__attribute__((address_space(3))) u32*)(lp), 16, 0, 0)

// ---- prep: block-range-fused {f32->bf16 cvt of hidden} + {4 weight
// transposes out[n*2048+k] = bf16(in[k*N+n])} ----------------------------
__global__ __launch_bounds__(256) void prep_kernel(
    const float* __restrict__ hidden, u16* __restrict__ hidbf,
    const float* __restrict__ wq, const float* __restrict__ wk,
    const float* __restrict__ wv, const float* __restrict__ wo,
    u16* __restrict__ Wt, u16* __restrict__ Wo2) {
  __shared__ float t[64][65];
  int blk = blockIdx.x;
  if (blk < 4096) {                     // cvt hidden: 4096*256 = 1M float4
    int i = blk * 256 + threadIdx.x;
    float4 v = ((const float4*)hidden)[i];
    ushort4 o;
    o.x = f2b(v.x); o.y = f2b(v.y); o.z = f2b(v.z); o.w = f2b(v.w);
    ((ushort4*)hidbf)[i] = o;
    return;
  }
  blk -= 4096;
  const float* in; u16* out; int N, nblk;
  if (blk < 1024)      { in = wq; out = Wt;                       N = 2048; nblk = blk; }
  else if (blk < 1280) { in = wk; out = Wt + (size_t)2048 * 2048; N = 512;  nblk = blk - 1024; }
  else if (blk < 1536) { in = wv; out = Wt + (size_t)2560 * 2048; N = 512;  nblk = blk - 1280; }
  else                 { in = wo; out = Wo2;                      N = 2048; nblk = blk - 1536; }
  int k0 = (nblk & 31) * 64, n0 = (nblk >> 5) * 64;
  int c = threadIdx.x & 63, r0 = threadIdx.x >> 6;
#pragma unroll
  for (int i = 0; i < 16; ++i) {
    int r = r0 + i * 4;
    t[r][c] = in[(size_t)(k0 + r) * N + n0 + c];
  }
  __syncthreads();
#pragma unroll
  for (int i = 0; i < 16; ++i) {
    int r = r0 + i * 4;
    out[(size_t)(n0 + r) * 2048 + k0 + c] = f2b(t[c][r]);
  }
}

// ------- bf16 GEMM: C[M][N] = A[M][K] * Bt[N][K]^T, 128x128 tile, BK=64 ----
// 2-phase double-buffered: stage(kt+1) issued before compute(kt), one
// barrier per k-step.
// EPI 0: Q/K bf16 stores with fused RoPE; V written TRANSPOSED to vt.
// EPI 1: f32 store to out (ldc 2048).
template <int EPI>
__global__ __launch_bounds__(256) void gemm_kernel(
    const u16* __restrict__ A, const u16* __restrict__ Bt, int K,
    u16* __restrict__ qb, u16* __restrict__ kb, u16* __restrict__ vt,
    float* __restrict__ out,
    const float* __restrict__ cosT, const float* __restrict__ sinT) {
  __shared__ u16 As[2][128 * 64];
  __shared__ u16 Bs[2][128 * 64];
  const int tid = threadIdx.x;
  const int w = tid >> 6, l = tid & 63;
  const int wr = w >> 1, wc = w & 1;
  const int lg = l >> 4, ll = l & 15;
  const int l8 = l >> 3, lc = l & 7;
  const int m0 = blockIdx.x * 128, n0 = blockIdx.y * 128;

  f32x4 acc[4][4] = {};

#define GSTAGE(KT, BUF)                                                       \
  {                                                                           \
    _Pragma("unroll")                                                         \
    for (int i = 0; i < 4; ++i) {                                             \
      int r0 = w * 32 + i * 8;                                                \
      int row = r0 + l8;                                                      \
      int cc = lc ^ (row & 7);                                                \
      GLL16(A  + (size_t)(m0 + row) * K + (KT) * 64 + cc * 8,                 \
            &As[BUF][r0 * 64]);                                               \
      GLL16(Bt + (size_t)(n0 + row) * K + (KT) * 64 + cc * 8,                 \
            &Bs[BUF][r0 * 64]);                                               \
    }                                                                         \
  }

  const int nkt = K >> 6;
  GSTAGE(0, 0);
  int cur = 0;
  for (int kt = 0; kt < nkt; ++kt) {
    __syncthreads();                       // stage(kt) landed (vmcnt drained)
    if (kt + 1 < nkt) GSTAGE(kt + 1, cur ^ 1);   // flies under compute below
#pragma unroll
    for (int kc = 0; kc < 2; ++kc) {
      int cblk = kc * 4 + lg;
      bf16x8 af[4], bfr[4];
#pragma unroll
      for (int mi = 0; mi < 4; ++mi) {
        int row = wr * 64 + mi * 16 + ll;
        af[mi] = *(const bf16x8*)&As[cur][row * 64 + ((cblk ^ (row & 7)) * 8)];
      }
#pragma unroll
      for (int ni = 0; ni < 4; ++ni) {
        int row = wc * 64 + ni * 16 + ll;
        bfr[ni] = *(const bf16x8*)&Bs[cur][row * 64 + ((cblk ^ (row & 7)) * 8)];
      }
#pragma unroll
      for (int mi = 0; mi < 4; ++mi)
#pragma unroll
        for (int ni = 0; ni < 4; ++ni)
          acc[mi][ni] = __builtin_amdgcn_mfma_f32_16x16x32_bf16(
              af[mi], bfr[ni], acc[mi][ni], 0, 0, 0);
    }
    cur ^= 1;
  }
#undef GSTAGE

  if constexpr (EPI == 0) {
    if (n0 >= 2560) {
      // V block: write V^T directly: vt[((b*8+kvh)*64+d)*1024 + s]
      const int cvbase = n0 - 2560;
#pragma unroll
      for (int mi = 0; mi < 4; ++mi)
#pragma unroll
        for (int ni = 0; ni < 4; ++ni) {
          int cv = cvbase + wc * 64 + ni * 16 + ll;          // 0..511
          int token0 = m0 + wr * 64 + mi * 16 + lg * 4;      // mult of 4
          int bb = token0 >> 10, s0 = token0 & 1023;
          size_t drow = (size_t)(bb * 8 + (cv >> 6)) * 64 + (cv & 63);
          ushort4 pk;
          pk.x = f2b(acc[mi][ni][0]); pk.y = f2b(acc[mi][ni][1]);
          pk.z = f2b(acc[mi][ni][2]); pk.w = f2b(acc[mi][ni][3]);
          *(ushort4*)&vt[drow * 1024 + s0] = pk;
        }
    } else {
      u16* dst; int ldc, c0;
      if (n0 < 2048) { dst = qb; ldc = 2048; c0 = n0; }
      else           { dst = kb; ldc = 512;  c0 = n0 - 2048; }
#pragma unroll
      for (int mi = 0; mi < 4; ++mi)
#pragma unroll
        for (int ni = 0; ni < 4; ++ni)
#pragma unroll
          for (int r = 0; r < 4; ++r) {
            int row = m0 + wr * 64 + mi * 16 + lg * 4 + r;
            int col = c0 + wc * 64 + ni * 16 + ll;
            // RoPE: head-dim coord d = ni*16+ll (c0, wc*64 are mults of 64)
            int d = ni * 16 + ll;
            int s = row & 1023;
            float cv = cosT[s * 64 + d], sv = sinT[s * 64 + d];
            float x  = acc[mi][ni][r];
            float xp = acc[mi][ni ^ 2][r];  // partner d +/- 32, same lane
            x = (ni < 2) ? (x * cv - xp * sv) : (x * cv + xp * sv);
            dst[(size_t)row * ldc + col] = f2b(x);
          }
    }
  } else {
#pragma unroll
    for (int mi = 0; mi < 4; ++mi)
#pragma unroll
      for (int ni = 0; ni < 4; ++ni)
#pragma unroll
        for (int r = 0; r < 4; ++r) {
          int row = m0 + wr * 64 + mi * 16 + lg * 4 + r;
          int col = n0 + wc * 64 + ni * 16 + ll;
          out[(size_t)row * 2048 + col] = acc[mi][ni][r];
        }
  }
}

// ------- attention: WG = (b, h, qt-pair), 4 waves x 16 q-rows per tile ----
// Each block does q-tiles qt1 and 15-qt1 (17 tile-iters total -> balanced).
// Fixed-shift softmax (scores bounded). K double-buffered in LDS with
// stage-early; V read DIRECT from global (L2-resident, reuse=1). Ps is
// wave-local -> no mid-iteration sync.
__global__ __launch_bounds__(256) void attn_kernel(
    const u16* __restrict__ Qb,   // [2048][2048] bf16 (post-RoPE)
    const u16* __restrict__ Kb,   // [2048][512]  bf16 (post-RoPE)
    const u16* __restrict__ Vt,   // [(b*8+kvh)*64 + d][1024] bf16
    const float* __restrict__ msk,// [2][1024]
    float* __restrict__ attn,     // [2][32][1024][1024] f32
    u16* __restrict__ ctx) {      // [2048][2048] bf16
  __shared__ u16 Ks[2][64 * 64];
  __shared__ float Ps[64 * 68];   // p tile f32, stride 68
  __shared__ u8 Msk[1024];

  const int tid = threadIdx.x, w = tid >> 6, l = tid & 63;
  const int lg = l >> 4, ll = l & 15;
  const int l8 = l >> 3, lc = l & 7;
  const int bid = blockIdx.x;
  const int qt1 = bid & 7;
  const int h = (bid >> 3) & 31;
  const int b = bid >> 8;
  const int kvh = h >> 2;
  const u16* __restrict__ Vg = Vt + (size_t)((b * 8 + kvh) * 64) * 1024;

  for (int i = tid; i < 1024; i += 256) Msk[i] = (msk[b * 1024 + i] != 0.f);

#define STAGE_K(KT, BUF)                                                      \
  {                                                                           \
    for (int j = 0; j < 2; ++j) {                                             \
      int r0 = w * 16 + j * 8;                                                \
      int row = r0 + l8;                                                      \
      int cc = lc ^ (row & 7);                                                \
      GLL16(Kb + (size_t)(b * 1024 + (KT) * 64 + row) * 512 + kvh * 64 +      \
                cc * 8,                                                       \
            &Ks[BUF][r0 * 64]);                                               \
    }                                                                         \
  }

  for (int half = 0; half < 2; ++half) {
    const int qt = half ? (15 - qt1) : qt1;
    const int qrow0 = qt * 64 + w * 16 + lg * 4;   // global q row of reg r=0

    // Q fragments (A-operand): row = ll, k contiguous
    bf16x8 qf[2];
    {
      const u16* qp = Qb + (size_t)(b * 1024 + qt * 64 + w * 16 + ll) * 2048 +
                      h * 64 + lg * 8;
      qf[0] = *(const bf16x8*)qp;
      qf[1] = *(const bf16x8*)(qp + 32);
    }

    // ---- pass 1: per-lane partial row sums of exp(s/8), dbuf K ----
    __syncthreads();                 // Ks free (prev use done), Msk visible
    STAGE_K(0, 0);
    float l_r[4] = {0.f, 0.f, 0.f, 0.f};
    for (int kt = 0; kt <= qt; ++kt) {
      const int c = kt & 1;
      __syncthreads();               // stage(kt) landed
      if (kt < qt) STAGE_K(kt + 1, c ^ 1);   // flies under compute below
      f32x4 sc[4] = {};
#pragma unroll
      for (int kc = 0; kc < 2; ++kc) {
        int cblk = kc * 4 + lg;
#pragma unroll
        for (int ns = 0; ns < 4; ++ns) {
          int row = ns * 16 + ll;
          bf16x8 kf = *(const bf16x8*)&Ks[c][row * 64 + ((cblk ^ (row & 7)) * 8)];
          sc[ns] = __builtin_amdgcn_mfma_f32_16x16x32_bf16(qf[kc], kf, sc[ns], 0, 0, 0);
        }
      }
#pragma unroll
      for (int ns = 0; ns < 4; ++ns) {
        int col = kt * 64 + ns * 16 + ll;
        bool mb = Msk[col];
#pragma unroll
        for (int r = 0; r < 4; ++r) {
          float e = __expf(sc[ns][r] * 0.125f);
          l_r[r] += (mb && col <= qrow0 + r) ? e : 0.f;
        }
      }
    }
    // one 16-lane reduce per row-register
#pragma unroll
    for (int r = 0; r < 4; ++r) {
#pragma unroll
      for (int mm = 1; mm < 16; mm <<= 1) l_r[r] += __shfl_xor(l_r[r], mm, 64);
    }
    float rinv[4];
#pragma unroll
    for (int r = 0; r < 4; ++r) rinv[r] = 1.f / l_r[r];

    // ---- pass 2: p -> Ps(wave-local) -> coalesced global; PV accum ----
    __syncthreads();                 // pass-1 reads done before restaging
    STAGE_K(0, 0);
    f32x4 cacc[4] = {};
    for (int kt = 0; kt <= qt; ++kt) {
      const int c = kt & 1;
      __syncthreads();               // stage(kt) landed
      if (kt < qt) STAGE_K(kt + 1, c ^ 1);
      f32x4 sc[4] = {};
#pragma unroll
      for (int kc = 0; kc < 2; ++kc) {
        int cblk = kc * 4 + lg;
#pragma unroll
        for (int ns = 0; ns < 4; ++ns) {
          int row = ns * 16 + ll;
          bf16x8 kf = *(const bf16x8*)&Ks[c][row * 64 + ((cblk ^ (row & 7)) * 8)];
          sc[ns] = __builtin_amdgcn_mfma_f32_16x16x32_bf16(qf[kc], kf, sc[ns], 0, 0, 0);
        }
      }
#pragma unroll
      for (int ns = 0; ns < 4; ++ns) {
        int col = kt * 64 + ns * 16 + ll;
        bool mb = Msk[col];
#pragma unroll
        for (int r = 0; r < 4; ++r) {
          float e = __expf(sc[ns][r] * 0.125f) * rinv[r];
          float p = (mb && col <= qrow0 + r) ? e : 0.f;
          Ps[(w * 16 + lg * 4 + r) * 68 + ns * 16 + ll] = p;   // wave-local
        }
      }
      // coalesced attn store from wave-local Ps rows
      {
        size_t rowbase = ((size_t)((b * 32 + h) * 1024 + qt * 64 + w * 16));
#pragma unroll
        for (int rr = 0; rr < 4; ++rr) {
          int lr = rr * 4 + lg;
          f32x4 pv4 = *(const f32x4*)&Ps[(w * 16 + lr) * 68 + ll * 4];
          *(f32x4*)&attn[(rowbase + lr) * 1024 + kt * 64 + ll * 4] = pv4;
        }
      }
      // PV: A-fragment from wave-local Ps; B-fragment direct from global V^T
#pragma unroll
      for (int kc = 0; kc < 2; ++kc) {
        const float* pp = &Ps[(w * 16 + ll) * 68 + kc * 32 + lg * 8];
        f32x4 plo = *(const f32x4*)pp;
        f32x4 phi = *(const f32x4*)(pp + 4);
        bf16x8 pa;
        pa[0] = (__bf16)plo[0]; pa[1] = (__bf16)plo[1];
        pa[2] = (__bf16)plo[2]; pa[3] = (__bf16)plo[3];
        pa[4] = (__bf16)phi[0]; pa[5] = (__bf16)phi[1];
        pa[6] = (__bf16)phi[2]; pa[7] = (__bf16)phi[3];
        int cblk = kc * 4 + lg;
#pragma unroll
        for (int ns = 0; ns < 4; ++ns) {
          int row = ns * 16 + ll;          // d index within head
          bf16x8 vf = *(const bf16x8*)&Vg[(size_t)row * 1024 + kt * 64 + cblk * 8];
          cacc[ns] = __builtin_amdgcn_mfma_f32_16x16x32_bf16(pa, vf, cacc[ns], 0, 0, 0);
        }
      }
    }

    // ctx out (token-major, bf16)
#pragma unroll
    for (int ns = 0; ns < 4; ++ns)
#pragma unroll
      for (int r = 0; r < 4; ++r) {
        int tok = b * 1024 + qt * 64 + w * 16 + lg * 4 + r;
        ctx[(size_t)tok * 2048 + h * 64 + ns * 16 + ll] = f2b(cacc[ns][r]);
      }

    // zero-fill the never-visited upper-triangle tiles (d_out is poisoned)
    int c00 = (qt + 1) * 64;
    int nzf = (1024 - c00) >> 2;
    if (nzf > 0) {
      size_t rb = ((size_t)((b * 32 + h) * 1024 + qt * 64)) * 1024;
      for (int i = tid; i < 64 * nzf; i += 256) {
        int rr = i / nzf;
        int cc4 = i - rr * nzf;
        float4 z = make_float4(0.f, 0.f, 0.f, 0.f);
        *(float4*)&attn[rb + (size_t)rr * 1024 + c00 + (size_t)cc4 * 4] = z;
      }
    }
  }
#undef STAGE_K
}

extern "C" void kernel_launch(void* const* d_in, const int* in_sizes, int n_in,
                              void* d_out, int out_size, void* d_ws, size_t ws_size,
                              hipStream_t stream) {
  const float* hidden = (const float*)d_in[0];
  const float* mask   = (const float*)d_in[1];
  const float* cosT   = (const float*)d_in[2];
  const float* sinT   = (const float*)d_in[3];
  const float* wq     = (const float*)d_in[4];
  const float* wk     = (const float*)d_in[5];
  const float* wv     = (const float*)d_in[6];
  const float* wo     = (const float*)d_in[7];

  char* ws = (char*)d_ws;
  u16* hidbf = (u16*)(ws);                      // 8 MiB; reused as ctx later
  u16* Wt    = (u16*)(ws + (8u << 20));         // 12 MiB [3072][2048] bf16 (wq|wk|wv)
  u16* Wo2   = (u16*)(ws + (20u << 20));        // 8 MiB wo^T
  u16* Qb    = (u16*)(ws + (28u << 20));        // 8 MiB
  u16* Kb    = (u16*)(ws + (36u << 20));        // 2 MiB
  u16* Vtg   = (u16*)(ws + (38u << 20));        // 2 MiB V^T

  float* outp  = (float*)d_out;
  float* attnp = outp + (size_t)2 * 1024 * 2048;

  prep_kernel<<<6656, 256, 0, stream>>>(hidden, hidbf, wq, wk, wv, wo, Wt, Wo2);
  gemm_kernel<0><<<dim3(16, 24), 256, 0, stream>>>(hidbf, Wt, 2048, Qb, Kb, Vtg,
                                                   nullptr, cosT, sinT);
  attn_kernel<<<512, 256, 0, stream>>>(Qb, Kb, Vtg, mask, attnp, hidbf);
  gemm_kernel<1><<<dim3(16, 16), 256, 0, stream>>>(hidbf, Wo2, 2048,
                                                   nullptr, nullptr, nullptr, outp,
                                                   nullptr, nullptr);
}

// Round 10
// 448.057 us; speedup vs baseline: 1.0816x; 1.0816x over previous
//
#include <hip/hip_runtime.h>

// LlamaAttention (B=2,S=1024,HID=2048,NH=32,NKV=8,D=64) on gfx950.
// R4: attn 2-phase pipeline, RoPE fused into QKV-GEMM epilogue.
// R5: GEMMs 2-phase double-buffered (one barrier/k-step).
// R7: prep fusion (cvt + 4 weight transposes), V^T written from gemm<0>.
// R9: REVERT R8's V-direct-read (regressed +20us: latency-exposed scattered
// PV loads). V is staged again via double-buffered LDS (R5 attn structure).

typedef unsigned short u16;
typedef unsigned char  u8;
typedef unsigned int   u32;
typedef __attribute__((ext_vector_type(4))) float  f32x4;
typedef __attribute__((ext_vector_type(8))) __bf16 bf16x8;

static __device__ __forceinline__ u16 f2b(float f) {
  u32 u = __builtin_bit_cast(u32, f);
  u = u + 0x7fffu + ((u >> 16) & 1u);   // round-to-nearest-even
  return (u16)(u >> 16);
}

// async global->LDS, 16B per lane; LDS dest is wave-uniform base + lane*16.
#define GLL16(gp, lp)                                                         \
  __builtin_amdgcn_global_load_lds(                                           \
      (__attribute__((address_space(1))) u32*)(gp),                           \
      (__attribute__((address_space(3))) u32*)(lp), 16, 0, 0)

// ---- prep: block-range-fused {f32->bf16 cvt of hidden} + {4 weight
// transposes out[n*2048+k] = bf16(in[k*N+n])} ----------------------------
__global__ __launch_bounds__(256) void prep_kernel(
    const float* __restrict__ hidden, u16* __restrict__ hidbf,
    const float* __restrict__ wq, const float* __restrict__ wk,
    const float* __restrict__ wv, const float* __restrict__ wo,
    u16* __restrict__ Wt, u16* __restrict__ Wo2) {
  __shared__ float t[64][65];
  int blk = blockIdx.x;
  if (blk < 4096) {                     // cvt hidden: 4096*256 = 1M float4
    int i = blk * 256 + threadIdx.x;
    float4 v = ((const float4*)hidden)[i];
    ushort4 o;
    o.x = f2b(v.x); o.y = f2b(v.y); o.z = f2b(v.z); o.w = f2b(v.w);
    ((ushort4*)hidbf)[i] = o;
    return;
  }
  blk -= 4096;
  const float* in; u16* out; int N, nblk;
  if (blk < 1024)      { in = wq; out = Wt;                       N = 2048; nblk = blk; }
  else if (blk < 1280) { in = wk; out = Wt + (size_t)2048 * 2048; N = 512;  nblk = blk - 1024; }
  else if (blk < 1536) { in = wv; out = Wt + (size_t)2560 * 2048; N = 512;  nblk = blk - 1280; }
  else                 { in = wo; out = Wo2;                      N = 2048; nblk = blk - 1536; }
  int k0 = (nblk & 31) * 64, n0 = (nblk >> 5) * 64;
  int c = threadIdx.x & 63, r0 = threadIdx.x >> 6;
#pragma unroll
  for (int i = 0; i < 16; ++i) {
    int r = r0 + i * 4;
    t[r][c] = in[(size_t)(k0 + r) * N + n0 + c];
  }
  __syncthreads();
#pragma unroll
  for (int i = 0; i < 16; ++i) {
    int r = r0 + i * 4;
    out[(size_t)(n0 + r) * 2048 + k0 + c] = f2b(t[c][r]);
  }
}

// ------- bf16 GEMM: C[M][N] = A[M][K] * Bt[N][K]^T, 128x128 tile, BK=64 ----
// 2-phase double-buffered: stage(kt+1) issued before compute(kt), one
// barrier per k-step.
// EPI 0: Q/K bf16 stores with fused RoPE; V written TRANSPOSED to vt.
// EPI 1: f32 store to out (ldc 2048).
template <int EPI>
__global__ __launch_bounds__(256) void gemm_kernel(
    const u16* __restrict__ A, const u16* __restrict__ Bt, int K,
    u16* __restrict__ qb, u16* __restrict__ kb, u16* __restrict__ vt,
    float* __restrict__ out,
    const float* __restrict__ cosT, const float* __restrict__ sinT) {
  __shared__ u16 As[2][128 * 64];
  __shared__ u16 Bs[2][128 * 64];
  const int tid = threadIdx.x;
  const int w = tid >> 6, l = tid & 63;
  const int wr = w >> 1, wc = w & 1;
  const int lg = l >> 4, ll = l & 15;
  const int l8 = l >> 3, lc = l & 7;
  const int m0 = blockIdx.x * 128, n0 = blockIdx.y * 128;

  f32x4 acc[4][4] = {};

#define GSTAGE(KT, BUF)                                                       \
  {                                                                           \
    _Pragma("unroll")                                                         \
    for (int i = 0; i < 4; ++i) {                                             \
      int r0 = w * 32 + i * 8;                                                \
      int row = r0 + l8;                                                      \
      int cc = lc ^ (row & 7);                                                \
      GLL16(A  + (size_t)(m0 + row) * K + (KT) * 64 + cc * 8,                 \
            &As[BUF][r0 * 64]);                                               \
      GLL16(Bt + (size_t)(n0 + row) * K + (KT) * 64 + cc * 8,                 \
            &Bs[BUF][r0 * 64]);                                               \
    }                                                                         \
  }

  const int nkt = K >> 6;
  GSTAGE(0, 0);
  int cur = 0;
  for (int kt = 0; kt < nkt; ++kt) {
    __syncthreads();                       // stage(kt) landed (vmcnt drained)
    if (kt + 1 < nkt) GSTAGE(kt + 1, cur ^ 1);   // flies under compute below
#pragma unroll
    for (int kc = 0; kc < 2; ++kc) {
      int cblk = kc * 4 + lg;
      bf16x8 af[4], bfr[4];
#pragma unroll
      for (int mi = 0; mi < 4; ++mi) {
        int row = wr * 64 + mi * 16 + ll;
        af[mi] = *(const bf16x8*)&As[cur][row * 64 + ((cblk ^ (row & 7)) * 8)];
      }
#pragma unroll
      for (int ni = 0; ni < 4; ++ni) {
        int row = wc * 64 + ni * 16 + ll;
        bfr[ni] = *(const bf16x8*)&Bs[cur][row * 64 + ((cblk ^ (row & 7)) * 8)];
      }
#pragma unroll
      for (int mi = 0; mi < 4; ++mi)
#pragma unroll
        for (int ni = 0; ni < 4; ++ni)
          acc[mi][ni] = __builtin_amdgcn_mfma_f32_16x16x32_bf16(
              af[mi], bfr[ni], acc[mi][ni], 0, 0, 0);
    }
    cur ^= 1;
  }
#undef GSTAGE

  if constexpr (EPI == 0) {
    if (n0 >= 2560) {
      // V block: write V^T directly: vt[((b*8+kvh)*64+d)*1024 + s]
      const int cvbase = n0 - 2560;
#pragma unroll
      for (int mi = 0; mi < 4; ++mi)
#pragma unroll
        for (int ni = 0; ni < 4; ++ni) {
          int cv = cvbase + wc * 64 + ni * 16 + ll;          // 0..511
          int token0 = m0 + wr * 64 + mi * 16 + lg * 4;      // mult of 4
          int bb = token0 >> 10, s0 = token0 & 1023;
          size_t drow = (size_t)(bb * 8 + (cv >> 6)) * 64 + (cv & 63);
          ushort4 pk;
          pk.x = f2b(acc[mi][ni][0]); pk.y = f2b(acc[mi][ni][1]);
          pk.z = f2b(acc[mi][ni][2]); pk.w = f2b(acc[mi][ni][3]);
          *(ushort4*)&vt[drow * 1024 + s0] = pk;
        }
    } else {
      u16* dst; int ldc, c0;
      if (n0 < 2048) { dst = qb; ldc = 2048; c0 = n0; }
      else           { dst = kb; ldc = 512;  c0 = n0 - 2048; }
#pragma unroll
      for (int mi = 0; mi < 4; ++mi)
#pragma unroll
        for (int ni = 0; ni < 4; ++ni)
#pragma unroll
          for (int r = 0; r < 4; ++r) {
            int row = m0 + wr * 64 + mi * 16 + lg * 4 + r;
            int col = c0 + wc * 64 + ni * 16 + ll;
            // RoPE: head-dim coord d = ni*16+ll (c0, wc*64 are mults of 64)
            int d = ni * 16 + ll;
            int s = row & 1023;
            float cv = cosT[s * 64 + d], sv = sinT[s * 64 + d];
            float x  = acc[mi][ni][r];
            float xp = acc[mi][ni ^ 2][r];  // partner d +/- 32, same lane
            x = (ni < 2) ? (x * cv - xp * sv) : (x * cv + xp * sv);
            dst[(size_t)row * ldc + col] = f2b(x);
          }
    }
  } else {
#pragma unroll
    for (int mi = 0; mi < 4; ++mi)
#pragma unroll
      for (int ni = 0; ni < 4; ++ni)
#pragma unroll
        for (int r = 0; r < 4; ++r) {
          int row = m0 + wr * 64 + mi * 16 + lg * 4 + r;
          int col = n0 + wc * 64 + ni * 16 + ll;
          out[(size_t)row * 2048 + col] = acc[mi][ni][r];
        }
  }
}

// ------- attention: WG = (b, h, qt-pair), 4 waves x 16 q-rows per tile ----
// Each block does q-tiles qt1 and 15-qt1 (17 tile-iters total -> balanced).
// Fixed-shift softmax (scores bounded). 2-phase pipeline: double-buffered
// K/V LDS, next tile's global_load_lds issued right after the top sync so
// it flies under QK/exp/PV. Ps is wave-local -> no mid-iteration sync.
__global__ __launch_bounds__(256) void attn_kernel(
    const u16* __restrict__ Qb,   // [2048][2048] bf16 (post-RoPE)
    const u16* __restrict__ Kb,   // [2048][512]  bf16 (post-RoPE)
    const u16* __restrict__ Vt,   // [(b*8+kvh)*64 + d][1024] bf16
    const float* __restrict__ msk,// [2][1024]
    float* __restrict__ attn,     // [2][32][1024][1024] f32
    u16* __restrict__ ctx) {      // [2048][2048] bf16
  __shared__ u16 Ks[2][64 * 64];
  __shared__ u16 Vs[2][64 * 64];
  __shared__ float Ps[64 * 68];   // p tile f32, stride 68
  __shared__ u8 Msk[1024];

  const int tid = threadIdx.x, w = tid >> 6, l = tid & 63;
  const int lg = l >> 4, ll = l & 15;
  const int l8 = l >> 3, lc = l & 7;
  const int bid = blockIdx.x;
  const int qt1 = bid & 7;
  const int h = (bid >> 3) & 31;
  const int b = bid >> 8;
  const int kvh = h >> 2;

  for (int i = tid; i < 1024; i += 256) Msk[i] = (msk[b * 1024 + i] != 0.f);

#define STAGE_K(KT, BUF)                                                      \
  {                                                                           \
    for (int j = 0; j < 2; ++j) {                                             \
      int r0 = w * 16 + j * 8;                                                \
      int row = r0 + l8;                                                      \
      int cc = lc ^ (row & 7);                                                \
      GLL16(Kb + (size_t)(b * 1024 + (KT) * 64 + row) * 512 + kvh * 64 +      \
                cc * 8,                                                       \
            &Ks[BUF][r0 * 64]);                                               \
    }                                                                         \
  }
#define STAGE_V(KT, BUF)                                                      \
  {                                                                           \
    for (int j = 0; j < 2; ++j) {                                             \
      int r0 = w * 16 + j * 8;                                                \
      int row = r0 + l8;                                                      \
      int cc = lc ^ (row & 7);                                                \
      GLL16(Vt + (size_t)((b * 8 + kvh) * 64 + row) * 1024 + (KT) * 64 +      \
                cc * 8,                                                       \
            &Vs[BUF][r0 * 64]);                                               \
    }                                                                         \
  }

  for (int half = 0; half < 2; ++half) {
    const int qt = half ? (15 - qt1) : qt1;
    const int qrow0 = qt * 64 + w * 16 + lg * 4;   // global q row of reg r=0

    // Q fragments (A-operand): row = ll, k contiguous
    bf16x8 qf[2];
    {
      const u16* qp = Qb + (size_t)(b * 1024 + qt * 64 + w * 16 + ll) * 2048 +
                      h * 64 + lg * 8;
      qf[0] = *(const bf16x8*)qp;
      qf[1] = *(const bf16x8*)(qp + 32);
    }

    // ---- pass 1: per-lane partial row sums of exp(s/8), dbuf K ----
    __syncthreads();                 // Ks free (prev use done), Msk visible
    STAGE_K(0, 0);
    float l_r[4] = {0.f, 0.f, 0.f, 0.f};
    for (int kt = 0; kt <= qt; ++kt) {
      const int c = kt & 1;
      __syncthreads();               // stage(kt) landed
      if (kt < qt) STAGE_K(kt + 1, c ^ 1);   // flies under compute below
      f32x4 sc[4] = {};
#pragma unroll
      for (int kc = 0; kc < 2; ++kc) {
        int cblk = kc * 4 + lg;
#pragma unroll
        for (int ns = 0; ns < 4; ++ns) {
          int row = ns * 16 + ll;
          bf16x8 kf = *(const bf16x8*)&Ks[c][row * 64 + ((cblk ^ (row & 7)) * 8)];
          sc[ns] = __builtin_amdgcn_mfma_f32_16x16x32_bf16(qf[kc], kf, sc[ns], 0, 0, 0);
        }
      }
#pragma unroll
      for (int ns = 0; ns < 4; ++ns) {
        int col = kt * 64 + ns * 16 + ll;
        bool mb = Msk[col];
#pragma unroll
        for (int r = 0; r < 4; ++r) {
          float e = __expf(sc[ns][r] * 0.125f);
          l_r[r] += (mb && col <= qrow0 + r) ? e : 0.f;
        }
      }
    }
    // one 16-lane reduce per row-register
#pragma unroll
    for (int r = 0; r < 4; ++r) {
#pragma unroll
      for (int mm = 1; mm < 16; mm <<= 1) l_r[r] += __shfl_xor(l_r[r], mm, 64);
    }
    float rinv[4];
#pragma unroll
    for (int r = 0; r < 4; ++r) rinv[r] = 1.f / l_r[r];

    // ---- pass 2: p -> Ps(wave-local) -> coalesced global; PV accum ----
    __syncthreads();                 // pass-1 reads done before restaging
    STAGE_K(0, 0);
    STAGE_V(0, 0);
    f32x4 cacc[4] = {};
    for (int kt = 0; kt <= qt; ++kt) {
      const int c = kt & 1;
      __syncthreads();               // stage(kt) landed
      if (kt < qt) { STAGE_K(kt + 1, c ^ 1); STAGE_V(kt + 1, c ^ 1); }
      f32x4 sc[4] = {};
#pragma unroll
      for (int kc = 0; kc < 2; ++kc) {
        int cblk = kc * 4 + lg;
#pragma unroll
        for (int ns = 0; ns < 4; ++ns) {
          int row = ns * 16 + ll;
          bf16x8 kf = *(const bf16x8*)&Ks[c][row * 64 + ((cblk ^ (row & 7)) * 8)];
          sc[ns] = __builtin_amdgcn_mfma_f32_16x16x32_bf16(qf[kc], kf, sc[ns], 0, 0, 0);
        }
      }
#pragma unroll
      for (int ns = 0; ns < 4; ++ns) {
        int col = kt * 64 + ns * 16 + ll;
        bool mb = Msk[col];
#pragma unroll
        for (int r = 0; r < 4; ++r) {
          float e = __expf(sc[ns][r] * 0.125f) * rinv[r];
          float p = (mb && col <= qrow0 + r) ? e : 0.f;
          Ps[(w * 16 + lg * 4 + r) * 68 + ns * 16 + ll] = p;   // wave-local
        }
      }
      // coalesced attn store from wave-local Ps rows
      {
        size_t rowbase = ((size_t)((b * 32 + h) * 1024 + qt * 64 + w * 16));
#pragma unroll
        for (int rr = 0; rr < 4; ++rr) {
          int lr = rr * 4 + lg;
          f32x4 pv4 = *(const f32x4*)&Ps[(w * 16 + lr) * 68 + ll * 4];
          *(f32x4*)&attn[(rowbase + lr) * 1024 + kt * 64 + ll * 4] = pv4;
        }
      }
      // PV: A-fragment from wave-local Ps (cvt f32->bf16 in regs)
#pragma unroll
      for (int kc = 0; kc < 2; ++kc) {
        const float* pp = &Ps[(w * 16 + ll) * 68 + kc * 32 + lg * 8];
        f32x4 plo = *(const f32x4*)pp;
        f32x4 phi = *(const f32x4*)(pp + 4);
        bf16x8 pa;
        pa[0] = (__bf16)plo[0]; pa[1] = (__bf16)plo[1];
        pa[2] = (__bf16)plo[2]; pa[3] = (__bf16)plo[3];
        pa[4] = (__bf16)phi[0]; pa[5] = (__bf16)phi[1];
        pa[6] = (__bf16)phi[2]; pa[7] = (__bf16)phi[3];
        int cblk = kc * 4 + lg;
#pragma unroll
        for (int ns = 0; ns < 4; ++ns) {
          int row = ns * 16 + ll;
          bf16x8 vf = *(const bf16x8*)&Vs[c][row * 64 + ((cblk ^ (row & 7)) * 8)];
          cacc[ns] = __builtin_amdgcn_mfma_f32_16x16x32_bf16(pa, vf, cacc[ns], 0, 0, 0);
        }
      }
    }

    // ctx out (token-major, bf16)
#pragma unroll
    for (int ns = 0; ns < 4; ++ns)
#pragma unroll
      for (int r = 0; r < 4; ++r) {
        int tok = b * 1024 + qt * 64 + w * 16 + lg * 4 + r;
        ctx[(size_t)tok * 2048 + h * 64 + ns * 16 + ll] = f2b(cacc[ns][r]);
      }

    // zero-fill the never-visited upper-triangle tiles (d_out is poisoned)
    int c00 = (qt + 1) * 64;
    int nzf = (1024 - c00) >> 2;
    if (nzf > 0) {
      size_t rb = ((size_t)((b * 32 + h) * 1024 + qt * 64)) * 1024;
      for (int i = tid; i < 64 * nzf; i += 256) {
        int rr = i / nzf;
        int cc4 = i - rr * nzf;
        float4 z = make_float4(0.f, 0.f, 0.f, 0.f);
        *(float4*)&attn[rb + (size_t)rr * 1024 + c00 + (size_t)cc4 * 4] = z;
      }
    }
  }
#undef STAGE_K
#undef STAGE_V
}

extern "C" void kernel_launch(void* const* d_in, const int* in_sizes, int n_in,
                              void* d_out, int out_size, void* d_ws, size_t ws_size,
                              hipStream_t stream) {
  const float* hidden = (const float*)d_in[0];
  const float* mask   = (const float*)d_in[1];
  const float* cosT   = (const float*)d_in[2];
  const float* sinT   = (const float*)d_in[3];
  const float* wq     = (const float*)d_in[4];
  const float* wk     = (const float*)d_in[5];
  const float* wv     = (const float*)d_in[6];
  const float* wo     = (const float*)d_in[7];

  char* ws = (char*)d_ws;
  u16* hidbf = (u16*)(ws);                      // 8 MiB; reused as ctx later
  u16* Wt    = (u16*)(ws + (8u << 20));         // 12 MiB [3072][2048] bf16 (wq|wk|wv)
  u16* Wo2   = (u16*)(ws + (20u << 20));        // 8 MiB wo^T
  u16* Qb    = (u16*)(ws + (28u << 20));        // 8 MiB
  u16* Kb    = (u16*)(ws + (36u << 20));        // 2 MiB
  u16* Vtg   = (u16*)(ws + (38u << 20));        // 2 MiB V^T

  float* outp  = (float*)d_out;
  float* attnp = outp + (size_t)2 * 1024 * 2048;

  prep_kernel<<<6656, 256, 0, stream>>>(hidden, hidbf, wq, wk, wv, wo, Wt, Wo2);
  gemm_kernel<0><<<dim3(16, 24), 256, 0, stream>>>(hidbf, Wt, 2048, Qb, Kb, Vtg,
                                                   nullptr, cosT, sinT);
  attn_kernel<<<512, 256, 0, stream>>>(Qb, Kb, Vtg, mask, attnp, hidbf);
  gemm_kernel<1><<<dim3(16, 16), 256, 0, stream>>>(hidbf, Wo2, 2048,
                                                   nullptr, nullptr, nullptr, outp,
                                                   nullptr, nullptr);
}